// Round 23
// baseline (1686.330 us; speedup 1.0000x reference)
//
#include <hip/hip_runtime.h>
#include <hip/hip_bf16.h>
#include <math.h>

// ---------------------------------------------------------------------------
// DepthlessTransformer forward. Round 23 = round 22 (proven, 1673us) + two
// init/readout-path trims (hot loop untouched):
//  (1) Init KV dedup: at it=0 toks[l] are identical (broadcast) and res_kvw
//      is shared -> Kc/Vc entries 0..5 are identical. Compute entry 0 only
//      (rmsnorm 384 rows, gemmKV nb=1, cache_fill grid(192,2)) and replicate
//      to entries 1..5 (7.9MB copy kernel).
//  (2) Readout-q fusion: 1-block rmsnorm + 1x512 GEMM -> one fused kernel
//      (fp32 serial dot; feeds only the readout attention).
// GEMM numerics: split-at-staging hi/lo bf16, 3 MFMAs, fp32 acc; W-side
// 2-deep static-named prefetch (absmax 0.015625 across r5-r22).
// D=512 H=8 DH=64 DI=512 L=6 NEX=6 FFI=1365 V=32000 B=2 N=192
// ---------------------------------------------------------------------------

#define EPSV 1.1920929e-07f
typedef __hip_bfloat16 bf16;
typedef __attribute__((ext_vector_type(4))) float f32x4;
typedef __attribute__((ext_vector_type(8))) short bf16x8;

// RTN split of 8 fp32 (two f32x4) into hi/lo bf16x8. Proven r5-22 numerics.
__device__ inline void split8r(f32x4 x0, f32x4 x1, bf16x8& h8, bf16x8& l8) {
#pragma unroll
  for (int i = 0; i < 4; ++i) {
    bf16 h0 = __float2bfloat16(x0[i]);
    h8[i] = __builtin_bit_cast(short, h0);
    l8[i] = __builtin_bit_cast(short, __float2bfloat16(x0[i] - __bfloat162float(h0)));
    bf16 h1 = __float2bfloat16(x1[i]);
    h8[i + 4] = __builtin_bit_cast(short, h1);
    l8[i + 4] = __builtin_bit_cast(short, __float2bfloat16(x1[i] - __bfloat162float(h1)));
  }
}

// ============== split-at-staging GEMM: C = A * W^T (+bias), fp32 in/out ====
// Template: BMN = square tile dim (128 or 64); MR = fragments per wave dim.
// Grid: blockIdx.x = m-tile, blockIdx.y = n-tile, blockIdx.z = batch.
// LDS: hi/lo bf16 tiles, row pitch 40 bf16 (80B, 16B-aligned) -> 2-way banks.
// A: 1-deep reg prefetch (L2-hot). W: 2-deep, static named buffers (HBM-cold).
// mode 0: plain (+optional bias). mode 1: GEGLU fused (interleaved rows).
// mode 2: dual output -- n-tiles >= Nsplit: W2->C2 (same A), plain.
// mode 3: dual kernel -- n-tiles < Nsplit: A*W->C plain (no bias);
//         >= Nsplit: A2*W2(+bias)->GEGLU->C2.
#define BKG 32
#define LDB 40
template <int BMN, int MR>
__global__ __launch_bounds__(256) void gemm_split_t(
    const float* __restrict__ A, const float* __restrict__ A2,
    const float* __restrict__ W, const float* __restrict__ W2,
    const float* __restrict__ bias,
    float* __restrict__ C, float* __restrict__ C2,
    int M, int N, int Nsplit, int K, int ldc, int ldc2,
    long long aStr, long long aStr2, long long wStr, long long wStr2,
    long long bStr, long long cStr, long long cStr2, int mode)
{
  int batch = blockIdx.z;
  int m0 = blockIdx.x * BMN, n0 = blockIdx.y * BMN;

  const float* Ab; const float* Wb; float* Cb; const float* biasb = nullptr;
  int Neff, ld; bool geglu;
  if ((mode == 2 || mode == 3) && n0 >= Nsplit) {
    Ab = ((mode == 3) ? A2 : A) + (size_t)batch * ((mode == 3) ? aStr2 : aStr);
    Wb = W2 + (size_t)batch * wStr2;
    Cb = C2 + (size_t)batch * cStr2;
    n0 -= Nsplit; Neff = N - Nsplit; ld = ldc2;
    geglu = (mode == 3);
    if (geglu && bias) biasb = bias + (size_t)batch * bStr;
  } else {
    Ab = A + (size_t)batch * aStr;
    Wb = W + (size_t)batch * wStr;
    Cb = C + (size_t)batch * cStr;
    Neff = (mode >= 2) ? Nsplit : N; ld = ldc;
    geglu = (mode == 1);
    if (mode <= 1 && bias) biasb = bias + (size_t)batch * bStr;
  }

  __shared__ short Ah[BMN * LDB], Al[BMN * LDB];
  __shared__ short Wh[BMN * LDB], Wl[BMN * LDB];

  int t = threadIdx.x;
  int wave = t >> 6, lane = t & 63;
  const int HALF = BMN / 2;
  const int NR = BMN / 64;                 // staged 64-row groups
  int wr = wave >> 1, wc = wave & 1;       // wave's HALFxHALF quadrant
  int fr = lane & 15, fq = lane >> 4;      // fragment row + k-group
  int srow = t >> 2;                       // staging rows r0+srow
  int scol = (t & 3) * 8;                  // float col 0,8,16,24

  f32x4 acc[MR][MR] = {};
  f32x4 a0[NR], a1[NR];            // A prefetch, 1-deep
  f32x4 wA0[NR], wA1[NR];          // W prefetch, even steps
  f32x4 wB0[NR], wB1[NR];          // W prefetch, odd steps

  const int nsteps = K / BKG;      // 16 (K=512) or 44 (K=1408): even, >=4

  auto loadA = [&](f32x4 (&d0)[NR], f32x4 (&d1)[NR], int kk) {
#pragma unroll
    for (int r = 0; r < NR; ++r) {
      const float* p = Ab + (size_t)(m0 + r * 64 + srow) * K + kk + scol;
      d0[r] = *(const f32x4*)p;  d1[r] = *(const f32x4*)(p + 4);
    }
  };
  auto loadW = [&](f32x4 (&d0)[NR], f32x4 (&d1)[NR], int kk) {
#pragma unroll
    for (int r = 0; r < NR; ++r) {
      const float* p = Wb + (size_t)(n0 + r * 64 + srow) * K + kk + scol;
      d0[r] = *(const f32x4*)p;  d1[r] = *(const f32x4*)(p + 4);
    }
  };
  auto writeTiles = [&](f32x4 (&x0)[NR], f32x4 (&x1)[NR],
                        f32x4 (&y0)[NR], f32x4 (&y1)[NR]) {
#pragma unroll
    for (int r = 0; r < NR; ++r) {
      int row = r * 64 + srow;
      bf16x8 h, l;
      split8r(x0[r], x1[r], h, l);
      *(bf16x8*)&Ah[row * LDB + scol] = h;
      *(bf16x8*)&Al[row * LDB + scol] = l;
      split8r(y0[r], y1[r], h, l);
      *(bf16x8*)&Wh[row * LDB + scol] = h;
      *(bf16x8*)&Wl[row * LDB + scol] = l;
    }
  };
  auto mfmaStep = [&]() {
    bf16x8 ah[MR], al[MR], wh[MR], wl[MR];
#pragma unroll
    for (int m = 0; m < MR; ++m) {
      int r = (wr * HALF + m * 16 + fr) * LDB + fq * 8;
      ah[m] = *(const bf16x8*)&Ah[r];
      al[m] = *(const bf16x8*)&Al[r];
    }
#pragma unroll
    for (int n = 0; n < MR; ++n) {
      int r = (wc * HALF + n * 16 + fr) * LDB + fq * 8;
      wh[n] = *(const bf16x8*)&Wh[r];
      wl[n] = *(const bf16x8*)&Wl[r];
    }
#pragma unroll
    for (int m = 0; m < MR; ++m)
#pragma unroll
      for (int n = 0; n < MR; ++n) {
        acc[m][n] = __builtin_amdgcn_mfma_f32_16x16x32_bf16(ah[m], wh[n], acc[m][n], 0, 0, 0);
        acc[m][n] = __builtin_amdgcn_mfma_f32_16x16x32_bf16(al[m], wh[n], acc[m][n], 0, 0, 0);
        acc[m][n] = __builtin_amdgcn_mfma_f32_16x16x32_bf16(ah[m], wl[n], acc[m][n], 0, 0, 0);
      }
  };

  // prologue: A step 0; W steps 0 and 1
  loadA(a0, a1, 0);
  loadW(wA0, wA1, 0);
  loadW(wB0, wB1, BKG);

  for (int step = 0; step < nsteps; step += 2) {
    // ---- even step: consume a*, wA* ----
    writeTiles(a0, a1, wA0, wA1);
    loadA(a0, a1, (step + 1) * BKG);
    if (step + 2 < nsteps) loadW(wA0, wA1, (step + 2) * BKG);
    __syncthreads();
    mfmaStep();
    __syncthreads();
    // ---- odd step: consume a*, wB* ----
    writeTiles(a0, a1, wB0, wB1);
    if (step + 2 < nsteps) loadA(a0, a1, (step + 2) * BKG);
    if (step + 3 < nsteps) loadW(wB0, wB1, (step + 3) * BKG);
    __syncthreads();
    mfmaStep();
    __syncthreads();
  }

  if (!geglu) {
#pragma unroll
    for (int m = 0; m < MR; ++m)
#pragma unroll
      for (int n = 0; n < MR; ++n) {
        int col = n0 + wc * HALF + n * 16 + fr;
        if (col >= Neff) continue;
        float bv = biasb ? biasb[col] : 0.f;
#pragma unroll
        for (int j = 0; j < 4; ++j) {
          int row = m0 + wr * HALF + m * 16 + fq * 4 + j;
          if (row < M) Cb[(size_t)row * ld + col] = acc[m][n][j] + bv;
        }
      }
  } else {
    // GEGLU: even col = sim, odd col = gate (interleaved weight rows).
#pragma unroll
    for (int m = 0; m < MR; ++m)
#pragma unroll
      for (int n = 0; n < MR; ++n) {
        int col = n0 + wc * HALF + n * 16 + fr;
        float bv = biasb[col];
#pragma unroll
        for (int j = 0; j < 4; ++j) {
          float z = acc[m][n][j] + bv;
          float zn = __shfl_xor(z, 1);   // partner: sim<->gate
          if (!(col & 1) && col < Neff) {
            float g = zn;
            float a = z * (0.5f * g * (1.f + erff(g * 0.70710678118654752f)));
            int row = m0 + wr * HALF + m * 16 + fq * 4 + j;
            if (row < M) Cb[(size_t)row * ld + (col >> 1)] = a;
          }
        }
      }
  }
}

// ====== FF-keys weight perm+pad: [6,2730,512] -> [6,2816,512] interleaved ==
__global__ void ffk_perm_kernel(const float* __restrict__ kw,
                                const float* __restrict__ kb,
                                float* __restrict__ wout, float* __restrict__ bout)
{
  size_t idx = (size_t)blockIdx.x * 256 + threadIdx.x;
  const size_t per = 2816ull * 512;
  if (idx < 6 * per) {
    int b = (int)(idx / per);
    size_t r2 = idx % per;
    int r = (int)(r2 >> 9), k = (int)(r2 & 511);
    float v = 0.f;
    if (r < 2730) {
      int c = (r >> 1) + (r & 1) * 1365;
      v = kw[((size_t)b * 2730 + c) * 512 + k];
    }
    wout[idx] = v;
  }
  if (idx < 6 * 2816) {
    int b = (int)(idx / 2816), r = (int)(idx % 2816);
    float v = 0.f;
    if (r < 2730) {
      int c = (r >> 1) + (r & 1) * 1365;
      v = kb[(size_t)b * 2730 + c];
    }
    bout[idx] = v;
  }
}

// ====== FF-vals weight pad: [6,512,1365] -> [6,512,1408] (K zero-pad) ======
__global__ void ffv_pad_kernel(const float* __restrict__ vw, float* __restrict__ wout)
{
  size_t idx = (size_t)blockIdx.x * 256 + threadIdx.x;
  const size_t total = 6ull * 512 * 1408;
  if (idx >= total) return;
  int k = (int)(idx % 1408);
  size_t nr = idx / 1408;   // b*512 + n
  wout[idx] = (k < 1365) ? vw[nr * 1365 + k] : 0.f;
}

// ================= rmsnorm over dim 512 (fp32 -> fp32) =====================
__global__ __launch_bounds__(256) void rmsnorm_kernel(
    const float* __restrict__ x, const float* __restrict__ w,
    float* __restrict__ out, int rows_per_w)
{
  int r = blockIdx.x;
  int t = threadIdx.x;
  const float* xr = x + (size_t)r * 512;
  float a = xr[t], b = xr[t + 256];
  float ss = a * a + b * b;
  for (int off = 32; off; off >>= 1) ss += __shfl_xor(ss, off);
  __shared__ float wsum[4];
  if ((t & 63) == 0) wsum[t >> 6] = ss;
  __syncthreads();
  float tot = wsum[0] + wsum[1] + wsum[2] + wsum[3];
  float rs = rsqrtf(tot * (1.f / 512.f) + EPSV);
  const float* wr = w + (size_t)(r / rows_per_w) * 512;
  out[(size_t)r * 512 + t] = a * rs * wr[t];
  out[(size_t)r * 512 + t + 256] = b * rs * wr[t + 256];
}

// ==== triple-output rmsnorm: one stats pass, three weights/outputs =========
__global__ __launch_bounds__(256) void rmsnorm3_kernel(
    const float* __restrict__ x, const float* __restrict__ w1,
    const float* __restrict__ w2, const float* __restrict__ w3,
    float* __restrict__ o1, float* __restrict__ o2, float* __restrict__ o3,
    int rows_per_w)
{
  int r = blockIdx.x;
  int t = threadIdx.x;
  const float* xr = x + (size_t)r * 512;
  float a = xr[t], b = xr[t + 256];
  float ss = a * a + b * b;
  for (int off = 32; off; off >>= 1) ss += __shfl_xor(ss, off);
  __shared__ float wsum[4];
  if ((t & 63) == 0) wsum[t >> 6] = ss;
  __syncthreads();
  float tot = wsum[0] + wsum[1] + wsum[2] + wsum[3];
  float rs = rsqrtf(tot * (1.f / 512.f) + EPSV);
  int wrow = r / rows_per_w;
  float ar = a * rs, br = b * rs;
  o1[(size_t)r * 512 + t]       = ar * w1[(size_t)wrow * 512 + t];
  o1[(size_t)r * 512 + t + 256] = br * w1[(size_t)wrow * 512 + t + 256];
  o2[(size_t)r * 512 + t]       = ar * w2[(size_t)wrow * 512 + t];
  o2[(size_t)r * 512 + t + 256] = br * w2[(size_t)wrow * 512 + t + 256];
  o3[(size_t)r * 512 + t]       = ar * w3[t];
  o3[(size_t)r * 512 + t + 256] = br * w3[t + 256];
}

// ============ fused readout q: rmsnorm(q_ro)*res_nw then x res_qw^T ========
// 1 block, 256 threads. fp32 serial dot (more accurate than split path).
__global__ __launch_bounds__(256) void readout_q_kernel(
    const float* __restrict__ qro, const float* __restrict__ nw,
    const float* __restrict__ qw, float* __restrict__ rq)
{
  __shared__ float rn[512];
  int t = threadIdx.x;
  float a = qro[t], b = qro[t + 256];
  float ss = a * a + b * b;
  for (int off = 32; off; off >>= 1) ss += __shfl_xor(ss, off);
  __shared__ float wsum[4];
  if ((t & 63) == 0) wsum[t >> 6] = ss;
  __syncthreads();
  float tot = wsum[0] + wsum[1] + wsum[2] + wsum[3];
  float rs = rsqrtf(tot * (1.f / 512.f) + EPSV);
  rn[t] = a * rs * nw[t];
  rn[t + 256] = b * rs * nw[t + 256];
  __syncthreads();
#pragma unroll
  for (int rep = 0; rep < 2; ++rep) {
    int e = t + rep * 256;
    const float* wr = qw + (size_t)e * 512;
    float acc = 0.f;
    for (int d = 0; d < 512; ++d) acc += rn[d] * wr[d];
    rq[e] = acc;
  }
}

// ====== replicate Kc/Vc entry 0 -> entries 1..5 (init broadcast dedup) =====
__global__ void replicate_kv_kernel(float* __restrict__ Kc, float* __restrict__ Vc)
{
  size_t idx = (size_t)blockIdx.x * 256 + threadIdx.x;
  const size_t per = 196608;            // entry stride
  if (idx >= 5 * per) return;
  size_t e = 1 + idx / per, i = idx % per;
  Kc[e * per + i] = Kc[i];
  Vc[e * per + i] = Vc[i];
}

// ================= broadcast tokens -> toks[L] =============================
__global__ void bcast_kernel(const float* __restrict__ tokens, float* __restrict__ toks)
{
  size_t idx = (size_t)blockIdx.x * 256 + threadIdx.x;
  const size_t total = (size_t)6 * 2 * 192 * 512;
  if (idx >= total) return;
  toks[idx] = tokens[idx % ((size_t)2 * 192 * 512)];
}

// ====== block self-attention, LDS K then V, 8 waves x 2 queries ===========
__global__ __launch_bounds__(512) void block_attn_kernel(
    const float* __restrict__ q, const float* __restrict__ kv, float* __restrict__ o)
{
  int h = blockIdx.y, lb = blockIdx.z;
  int t = threadIdx.x;
  int wave = t >> 6, lane = t & 63;
  int i0 = blockIdx.x * 16 + wave * 2;

  __shared__ float Ks[192][65];    // 49,920 B (K, then reused for V)
  __shared__ float qs[8][2][64];   // 4 KB
  __shared__ float ps[16][192];    // 12 KB

  const float* kb = kv + (size_t)lb * 192 * 1024 + h * 64;
#pragma unroll
  for (int c = 0; c < 24; ++c) {
    int idx = c * 512 + t;
    int row = idx >> 6, col = idx & 63;
    Ks[row][col] = kb[(size_t)row * 1024 + col];
  }
#pragma unroll
  for (int qq = 0; qq < 2; ++qq)
    qs[wave][qq][lane] = q[((size_t)(lb * 192 + i0 + qq)) * 512 + h * 64 + lane];
  __syncthreads();

  float s[2][3];
#pragma unroll
  for (int r = 0; r < 3; ++r) {
    int j = lane + r * 64;
    float a0 = 0.f, a1 = 0.f;
#pragma unroll 8
    for (int d = 0; d < 64; ++d) {
      float kvl = Ks[j][d];
      a0 += qs[wave][0][d] * kvl;
      a1 += qs[wave][1][d] * kvl;
    }
    s[0][r] = a0;
    s[1][r] = a1;
  }
#pragma unroll
  for (int qq = 0; qq < 2; ++qq) {
    float mx = fmaxf(fmaxf(s[qq][0], s[qq][1]), s[qq][2]);
    for (int off = 32; off; off >>= 1) mx = fmaxf(mx, __shfl_xor(mx, off));
    float sum = 0.f;
#pragma unroll
    for (int r = 0; r < 3; ++r) { s[qq][r] = expf(s[qq][r] - mx); sum += s[qq][r]; }
    for (int off = 32; off; off >>= 1) sum += __shfl_xor(sum, off);
    float inv = 1.f / sum;
#pragma unroll
    for (int r = 0; r < 3; ++r) ps[wave * 2 + qq][lane + r * 64] = s[qq][r] * inv;
  }

  // ---- phase 2: stage V over K (all waves done with Ks), PV from LDS ----
  __syncthreads();
  const float* vb = kb + 512;
#pragma unroll
  for (int c = 0; c < 24; ++c) {
    int idx = c * 512 + t;
    int row = idx >> 6, col = idx & 63;
    Ks[row][col] = vb[(size_t)row * 1024 + col];
  }
  __syncthreads();
  float acc0 = 0.f, acc1 = 0.f;
  for (int j = 0; j < 192; ++j) {
    float v = Ks[j][lane];
    acc0 += ps[wave * 2][j] * v;
    acc1 += ps[wave * 2 + 1][j] * v;
  }
  o[((size_t)(lb * 192 + i0)) * 512 + h * 64 + lane] = acc0;
  o[((size_t)(lb * 192 + i0 + 1)) * 512 + h * 64 + lane] = acc1;
}

// ================= pooled attention, K/V amortized over 6 queries ==========
__global__ __launch_bounds__(64) void pooled_attn_kernel(
    const float* __restrict__ q, const float* __restrict__ Kc,
    const float* __restrict__ Vc, float* __restrict__ o, int M, int mode)
{
  int n = blockIdx.x, h = blockIdx.y, z = blockIdx.z;
  int lane = threadIdx.x;
  int nq = mode ? 1 : 6;

  __shared__ float Ks[80][65];    // 20,800 B
  __shared__ float qs[6][64];
  __shared__ float p[6][128];

  for (int m = 0; m < M; ++m)
    Ks[m][lane] = Kc[(((size_t)m * 2 + z) * 192 + n) * 512 + h * 64 + lane];
  for (int jj = 0; jj < nq; ++jj) {
    const float* qrow = mode ? (q + h * 64)
                             : (q + ((size_t)((z * 6 + jj) * 192 + n)) * 512 + h * 64);
    qs[jj][lane] = qrow[lane];
  }
  __syncthreads();

  float d0[6] = {}, d1[6] = {};
  int m1 = lane + 64;
#pragma unroll 4
  for (int d = 0; d < 64; ++d) {
    float k0 = Ks[lane][d];
    float k1 = Ks[m1 & 79][d];
#pragma unroll
    for (int jj = 0; jj < 6; ++jj) {
      float qv = qs[jj][d];
      d0[jj] += qv * k0;
      d1[jj] += qv * k1;
    }
  }
  float acc[6] = {};
#pragma unroll
  for (int jj = 0; jj < 6; ++jj) {
    if (jj >= nq) break;
    float s0 = (lane < M) ? d0[jj] : -1e30f;
    float s1 = (m1 < M) ? d1[jj] : -1e30f;
    float mx = fmaxf(s0, s1);
    for (int off = 32; off; off >>= 1) mx = fmaxf(mx, __shfl_xor(mx, off));
    float e0 = (lane < M) ? expf(s0 - mx) : 0.f;
    float e1 = (m1 < M) ? expf(s1 - mx) : 0.f;
    float sum = e0 + e1;
    for (int off = 32; off; off >>= 1) sum += __shfl_xor(sum, off);
    float inv = 1.f / sum;
    p[jj][lane] = e0 * inv;
    p[jj][m1] = e1 * inv;
  }
  __syncthreads();

  for (int m = 0; m < M; ++m) {
    float v = Vc[(((size_t)m * 2 + z) * 192 + n) * 512 + h * 64 + lane];
#pragma unroll
    for (int jj = 0; jj < 6; ++jj) acc[jj] += p[jj][m] * v;
  }
#pragma unroll
  for (int jj = 0; jj < 6; ++jj) {
    if (jj >= nq) break;
    int orow = mode ? (z * 192 + n) : ((z * 6 + jj) * 192 + n);
    o[(size_t)orow * 512 + h * 64 + lane] = acc[jj];
  }
}

// ========= kv-cache fill, K-only (per-head key rmsnorm) ====================
__global__ __launch_bounds__(128) void cache_fill_kernel(
    const float* __restrict__ kvk, const float* __restrict__ knw,
    float* __restrict__ Kc, int base_e)
{
  int n = blockIdx.x;
  int t = blockIdx.y;
  int g = t >> 1, b = t & 1;
  int e = base_e + g;
  int lane = threadIdx.x;  // 128 lanes x 4 cols; 16 lanes per head
  const float* src = kvk + ((size_t)t * 192 + n) * 512;
  float k4[4];
  float ss = 0.f;
#pragma unroll
  for (int u = 0; u < 4; ++u) { k4[u] = src[lane * 4 + u]; ss += k4[u] * k4[u]; }
  for (int off = 8; off; off >>= 1) ss += __shfl_xor(ss, off, 16);
  float rs = rsqrtf(ss * (1.f / 64.f) + EPSV);
  float* kd = Kc + (((size_t)e * 2 + b) * 192 + n) * 512;
#pragma unroll
  for (int u = 0; u < 4; ++u) {
    int c = lane * 4 + u;
    kd[c] = k4[u] * rs * knw[c & 63];
  }
}

// ===========================================================================
extern "C" void kernel_launch(void* const* d_in, const int* in_sizes, int n_in,
                              void* d_out, int out_size, void* d_ws, size_t ws_size,
                              hipStream_t stream)
{
  const float* tokens   = (const float*)d_in[0];
  const float* attn_nw  = (const float*)d_in[1];
  const float* attn_qw  = (const float*)d_in[2];
  const float* attn_kvw = (const float*)d_in[3];
  const float* attn_ow  = (const float*)d_in[4];
  const float* ff_nw    = (const float*)d_in[5];
  const float* ff_kw    = (const float*)d_in[6];
  const float* ff_kb    = (const float*)d_in[7];
  const float* ff_vw    = (const float*)d_in[8];
  const float* ff_vb    = (const float*)d_in[9];
  const float* res_nw   = (const float*)d_in[10];
  const float* res_knw  = (const float*)d_in[11];
  const float* res_qw   = (const float*)d_in[12];
  const float* res_kvw  = (const float*)d_in[13];
  const float* res_ow   = (const float*)d_in[14];
  const float* q_ro     = (const float*)d_in[15];
  const float* ro_nw    = (const float*)d_in[16];
  const float* ro_w     = (const float*)d_in[17];
  float* out = (float*)d_out;

  // ---- workspace carve-up (55,461,376 floats = 221.9 MB) ----
  float* ws = (float*)d_ws;
  const size_t NEED = 55461376ull * 4ull;
  if (ws_size < NEED) return;
  float* ffk_w   = ws;  ws += 6ull * 2816 * 512;   // 8,650,752 (perm+pad fp32)
  float* ffk_b   = ws;  ws += 6ull * 2816;         // 16,896
  float* ffv_w   = ws;  ws += 6ull * 512 * 1408;   // 4,325,376 (K-pad fp32)
  float* toks    = ws;  ws += 1179648;             // [6,2,192,512]
  float* hbuf    = ws;  ws += 2359296;             // [<=4608,512]
  float* hbuf3   = ws;  ws += 1179648;             // res-normed toks (persistent)
  float* msgbuf  = ws;  ws += 2359296;             // [2,6,2,192,512]
  float* scratch = ws;  ws += 4718592;             // union region
  float* rqn     = ws;  ws += 512;
  float* rq      = ws;  ws += 512;
  float* Kc      = ws;  ws += 15335424;            // [78,2,192,512], entry stride 196608
  float* Vc      = ws;  ws += 15335424;            // [78,2,192,512], entry stride 196608
  (void)rqn;
  // scratch union (all uses strictly serialized on `stream`):
  float* qbuf   = scratch;                 // [2304,512]
  float* kvbuf  = scratch + 1179648;       // [12,192,1024]
  float* obuf   = scratch + 3538944;       // [2304,512]
  float* kvk    = scratch;                 // [<=24,192,512] = 2,359,296
  float* act    = scratch;                 // [2304,1408] = 3,244,032
  float* hbuf2  = hbuf + 1179648;          // ff-normed rows (dead before 4608-row rmsnorm)
  // readout aliases (msgbuf dead by then):
  float* robuf  = msgbuf;                  // [384,512]
  float* robuf2 = msgbuf + 196608;         // [384,512]
  float* ronorm = msgbuf + 393216;         // [384,512]

  auto gemm = [&](const float* A, const float* W, const float* bias, float* C,
                  int M, int N, int K, int ldc,
                  long long aStr, long long wStr, long long bStr, long long cStr,
                  int nb, int mode) {
    int gx = (N + 127) / 128, gy = (M + 127) / 128;
    if (mode == 0 && gx * gy * nb <= 300) {
      dim3 g((M + 63) / 64, (N + 63) / 64, nb);   // x = m-tiles, y = n-tiles
      hipLaunchKernelGGL((gemm_split_t<64, 2>), g, dim3(256), 0, stream,
                         A, A, W, W, bias, C, C, M, N, N, K, ldc, ldc,
                         aStr, 0ll, wStr, 0ll, bStr, cStr, 0ll, mode);
    } else {
      dim3 g(gy, gx, nb);                          // x = m-tiles, y = n-tiles
      hipLaunchKernelGGL((gemm_split_t<128, 4>), g, dim3(256), 0, stream,
                         A, A, W, W, bias, C, C, M, N, N, K, ldc, ldc,
                         aStr, 0ll, wStr, 0ll, bStr, cStr, 0ll, mode);
    }
  };
  // merged dual-output GEMM (mode 2), 64^2 tiles (same A both halves)
  auto gemm2 = [&](const float* A, const float* W, const float* W2,
                   float* C, float* C2, int M, int N, int Nsplit, int K,
                   int ldc, int ldc2, long long aStr, long long wStr,
                   long long wStr2, long long cStr, long long cStr2, int nb) {
    dim3 g((M + 63) / 64, (N + 63) / 64, nb);
    hipLaunchKernelGGL((gemm_split_t<64, 2>), g, dim3(256), 0, stream,
                       A, A, W, W2, nullptr, C, C2, M, N, Nsplit, K, ldc, ldc2,
                       aStr, 0ll, wStr, wStr2, 0ll, cStr, cStr2, 2);
  };
  // merged dual-kernel GEMM (mode 3): part1 plain A*W->C, part2 GEGLU
  auto gemm3 = [&](const float* A, const float* A2, const float* W,
                   const float* W2, const float* bias, float* C, float* C2,
                   int M, int N, int Nsplit, int K, int ldc, int ldc2,
                   long long aStr, long long aStr2, long long wStr,
                   long long wStr2, long long bStr, long long cStr,
                   long long cStr2, int nb) {
    dim3 g((M + 63) / 64, (N + 63) / 64, nb);
    hipLaunchKernelGGL((gemm_split_t<64, 2>), g, dim3(256), 0, stream,
                       A, A2, W, W2, bias, C, C2, M, N, Nsplit, K, ldc, ldc2,
                       aStr, aStr2, wStr, wStr2, bStr, cStr, cStr2, 3);
  };
  // kv-cache GEMM: K half -> kvk (compact), V half -> Vc directly (mode 2).
  auto gemmKV = [&](const float* A, float* Vdst, int nb) {
    dim3 g(6, 16, nb);   // 384/64 m-tiles, 1024/64 n-tiles
    hipLaunchKernelGGL((gemm_split_t<64, 2>), g, dim3(256), 0, stream,
                       A, A, res_kvw, res_kvw + 512 * 512, nullptr, kvk, Vdst,
                       384, 1024, 512, 512, 512, 512,
                       196608ll, 0ll, 0ll, 0ll, 0ll, 196608ll, 196608ll, 2);
  };

  // ---- FF weight prep (perm+pad) ----
  hipLaunchKernelGGL(ffk_perm_kernel, dim3((unsigned)((6ull * 2816 * 512 + 255) / 256)),
                     dim3(256), 0, stream, ff_kw, ff_kb, ffk_w, ffk_b);
  hipLaunchKernelGGL(ffv_pad_kernel, dim3((unsigned)((6ull * 512 * 1408 + 255) / 256)),
                     dim3(256), 0, stream, ff_vw, ffv_w);

  // ---- init: toks = broadcast(tokens); cache msg0 (entries 0..5 equal) ----
  {
    const int total = 6 * 2 * 192 * 512;
    hipLaunchKernelGGL(bcast_kernel, dim3((total + 255) / 256), dim3(256), 0, stream,
                       tokens, toks);
  }
  // entry 0 only: toks[l] identical at init, res_kvw shared -> e0..e5 equal
  hipLaunchKernelGGL(rmsnorm_kernel, dim3(384), dim3(256), 0, stream,
                     toks, res_nw, hbuf, 384);
  gemmKV(hbuf, Vc, 1);
  hipLaunchKernelGGL(cache_fill_kernel, dim3(192, 2), dim3(128), 0, stream,
                     kvk, res_knw, Kc, 0);
  hipLaunchKernelGGL(replicate_kv_kernel,
                     dim3((unsigned)((5ull * 196608 + 255) / 256)), dim3(256),
                     0, stream, Kc, Vc);

  for (int it = 0; it < 6; ++it) {
    // ---- norms for all three consumers of toks (one stats pass) ----
    hipLaunchKernelGGL(rmsnorm3_kernel, dim3(2304), dim3(256), 0, stream,
                       toks, attn_nw, ff_nw, res_nw, hbuf, hbuf2, hbuf3, 384);
    // ---- block self-attention -> msgbuf[0] (q+kv in ONE dispatch) ----
    gemm2(hbuf, attn_qw, attn_kvw, qbuf, kvbuf, 384, 1536, 512, 512, 512, 1024,
          196608, 262144, 524288, 196608, 393216, 6);
    hipLaunchKernelGGL(block_attn_kernel, dim3(12, 8, 12), dim3(512), 0, stream,
                       qbuf, kvbuf, obuf);
    // ---- attn-out + FF-keys GEGLU merged (both K=512) ----
    gemm3(obuf, hbuf2, attn_ow, ffk_w, ffk_b, msgbuf, act,
          384, 512 + 2730, 512, 512, 512, 1408,
          196608, 196608, 262144, 1441792, 2816, 196608, 540672, 6);
    // ---- FF-vals -> msgbuf[1] ----
    gemm(act, ffv_w, ff_vb, msgbuf + 1179648, 384, 512, 1408, 512,
         540672, 720896, 512, 196608, 6, 0);
    // ---- cache kv for the two new messages (V direct to Vc) ----
    hipLaunchKernelGGL(rmsnorm_kernel, dim3(4608), dim3(256), 0, stream,
                       msgbuf, res_nw, hbuf, 4608);
    gemmKV(hbuf, Vc + (size_t)(2 * it + 1) * 6 * 196608, 12);  // clobbers act (dead)
    hipLaunchKernelGGL(cache_fill_kernel, dim3(192, 24), dim3(128), 0, stream,
                       kvk, res_knw, Kc, (2 * it + 1) * 6);
    if (it == 5) break;
    // ---- pooled cross-attention over all cached entries -> new toks ----
    gemm(hbuf3, res_qw, nullptr, qbuf, 2304, 512, 512, 512,
         0, 0, 0, 0, 1, 0);                          // clobbers kvk (dead)
    hipLaunchKernelGGL(pooled_attn_kernel, dim3(192, 8, 2), dim3(64), 0, stream,
                       qbuf, Kc, Vc, obuf, (3 + 2 * it) * 6, 0);
    gemm(obuf, res_ow, nullptr, toks, 2304, 512, 512, 512,
         0, 0, 0, 0, 1, 0);
  }

  // ---- readout ----
  hipLaunchKernelGGL(readout_q_kernel, dim3(1), dim3(256), 0, stream,
                     q_ro, res_nw, res_qw, rq);
  hipLaunchKernelGGL(pooled_attn_kernel, dim3(192, 8, 2), dim3(64), 0, stream,
                     rq, Kc, Vc, robuf, 78, 1);
  gemm(robuf, res_ow, nullptr, robuf2, 384, 512, 512, 512, 0, 0, 0, 0, 1, 0);
  hipLaunchKernelGGL(rmsnorm_kernel, dim3(384), dim3(256), 0, stream,
                     robuf2, ro_nw, ronorm, 384);
  gemm(ronorm, ro_w, nullptr, out, 384, 32000, 512, 32000, 0, 0, 0, 0, 1, 0);
}

// Round 24
// 1672.152 us; speedup vs baseline: 1.0085x; 1.0085x over previous
//
#include <hip/hip_runtime.h>
#include <hip/hip_bf16.h>
#include <math.h>

// ---------------------------------------------------------------------------
// DepthlessTransformer forward. Round 24 = exact revert to round 22 (proven
// fastest: 1673us, absmax 0.015625). Round 23's init-dedup + readout-fusion
// trims measured neutral-to-negative (1686us) and are dropped.
// Final structure: split-bf16 MFMA GEMMs (hi/lo RTN split at staging, 3
// MFMAs, fp32 acc, W-side 2-deep static prefetch, 64^2/128^2 tile routing,
// merged q+kv / attn-out+GEGLU / direct-V dual-output dispatches), LDS-staged
// attention kernels, pooled-attention K/V dedup + 6-query amortization,
// shared-stats triple rmsnorm.
// D=512 H=8 DH=64 DI=512 L=6 NEX=6 FFI=1365 V=32000 B=2 N=192
// ---------------------------------------------------------------------------

#define EPSV 1.1920929e-07f
typedef __hip_bfloat16 bf16;
typedef __attribute__((ext_vector_type(4))) float f32x4;
typedef __attribute__((ext_vector_type(8))) short bf16x8;

// RTN split of 8 fp32 (two f32x4) into hi/lo bf16x8. Proven r5-22 numerics.
__device__ inline void split8r(f32x4 x0, f32x4 x1, bf16x8& h8, bf16x8& l8) {
#pragma unroll
  for (int i = 0; i < 4; ++i) {
    bf16 h0 = __float2bfloat16(x0[i]);
    h8[i] = __builtin_bit_cast(short, h0);
    l8[i] = __builtin_bit_cast(short, __float2bfloat16(x0[i] - __bfloat162float(h0)));
    bf16 h1 = __float2bfloat16(x1[i]);
    h8[i + 4] = __builtin_bit_cast(short, h1);
    l8[i + 4] = __builtin_bit_cast(short, __float2bfloat16(x1[i] - __bfloat162float(h1)));
  }
}

// ============== split-at-staging GEMM: C = A * W^T (+bias), fp32 in/out ====
// Template: BMN = square tile dim (128 or 64); MR = fragments per wave dim.
// Grid: blockIdx.x = m-tile, blockIdx.y = n-tile, blockIdx.z = batch.
// LDS: hi/lo bf16 tiles, row pitch 40 bf16 (80B, 16B-aligned) -> 2-way banks.
// A: 1-deep reg prefetch (L2-hot). W: 2-deep, static named buffers (HBM-cold).
// mode 0: plain (+optional bias). mode 1: GEGLU fused (interleaved rows).
// mode 2: dual output -- n-tiles >= Nsplit: W2->C2 (same A), plain.
// mode 3: dual kernel -- n-tiles < Nsplit: A*W->C plain (no bias);
//         >= Nsplit: A2*W2(+bias)->GEGLU->C2.
#define BKG 32
#define LDB 40
template <int BMN, int MR>
__global__ __launch_bounds__(256) void gemm_split_t(
    const float* __restrict__ A, const float* __restrict__ A2,
    const float* __restrict__ W, const float* __restrict__ W2,
    const float* __restrict__ bias,
    float* __restrict__ C, float* __restrict__ C2,
    int M, int N, int Nsplit, int K, int ldc, int ldc2,
    long long aStr, long long aStr2, long long wStr, long long wStr2,
    long long bStr, long long cStr, long long cStr2, int mode)
{
  int batch = blockIdx.z;
  int m0 = blockIdx.x * BMN, n0 = blockIdx.y * BMN;

  const float* Ab; const float* Wb; float* Cb; const float* biasb = nullptr;
  int Neff, ld; bool geglu;
  if ((mode == 2 || mode == 3) && n0 >= Nsplit) {
    Ab = ((mode == 3) ? A2 : A) + (size_t)batch * ((mode == 3) ? aStr2 : aStr);
    Wb = W2 + (size_t)batch * wStr2;
    Cb = C2 + (size_t)batch * cStr2;
    n0 -= Nsplit; Neff = N - Nsplit; ld = ldc2;
    geglu = (mode == 3);
    if (geglu && bias) biasb = bias + (size_t)batch * bStr;
  } else {
    Ab = A + (size_t)batch * aStr;
    Wb = W + (size_t)batch * wStr;
    Cb = C + (size_t)batch * cStr;
    Neff = (mode >= 2) ? Nsplit : N; ld = ldc;
    geglu = (mode == 1);
    if (mode <= 1 && bias) biasb = bias + (size_t)batch * bStr;
  }

  __shared__ short Ah[BMN * LDB], Al[BMN * LDB];
  __shared__ short Wh[BMN * LDB], Wl[BMN * LDB];

  int t = threadIdx.x;
  int wave = t >> 6, lane = t & 63;
  const int HALF = BMN / 2;
  const int NR = BMN / 64;                 // staged 64-row groups
  int wr = wave >> 1, wc = wave & 1;       // wave's HALFxHALF quadrant
  int fr = lane & 15, fq = lane >> 4;      // fragment row + k-group
  int srow = t >> 2;                       // staging rows r0+srow
  int scol = (t & 3) * 8;                  // float col 0,8,16,24

  f32x4 acc[MR][MR] = {};
  f32x4 a0[NR], a1[NR];            // A prefetch, 1-deep
  f32x4 wA0[NR], wA1[NR];          // W prefetch, even steps
  f32x4 wB0[NR], wB1[NR];          // W prefetch, odd steps

  const int nsteps = K / BKG;      // 16 (K=512) or 44 (K=1408): even, >=4

  auto loadA = [&](f32x4 (&d0)[NR], f32x4 (&d1)[NR], int kk) {
#pragma unroll
    for (int r = 0; r < NR; ++r) {
      const float* p = Ab + (size_t)(m0 + r * 64 + srow) * K + kk + scol;
      d0[r] = *(const f32x4*)p;  d1[r] = *(const f32x4*)(p + 4);
    }
  };
  auto loadW = [&](f32x4 (&d0)[NR], f32x4 (&d1)[NR], int kk) {
#pragma unroll
    for (int r = 0; r < NR; ++r) {
      const float* p = Wb + (size_t)(n0 + r * 64 + srow) * K + kk + scol;
      d0[r] = *(const f32x4*)p;  d1[r] = *(const f32x4*)(p + 4);
    }
  };
  auto writeTiles = [&](f32x4 (&x0)[NR], f32x4 (&x1)[NR],
                        f32x4 (&y0)[NR], f32x4 (&y1)[NR]) {
#pragma unroll
    for (int r = 0; r < NR; ++r) {
      int row = r * 64 + srow;
      bf16x8 h, l;
      split8r(x0[r], x1[r], h, l);
      *(bf16x8*)&Ah[row * LDB + scol] = h;
      *(bf16x8*)&Al[row * LDB + scol] = l;
      split8r(y0[r], y1[r], h, l);
      *(bf16x8*)&Wh[row * LDB + scol] = h;
      *(bf16x8*)&Wl[row * LDB + scol] = l;
    }
  };
  auto mfmaStep = [&]() {
    bf16x8 ah[MR], al[MR], wh[MR], wl[MR];
#pragma unroll
    for (int m = 0; m < MR; ++m) {
      int r = (wr * HALF + m * 16 + fr) * LDB + fq * 8;
      ah[m] = *(const bf16x8*)&Ah[r];
      al[m] = *(const bf16x8*)&Al[r];
    }
#pragma unroll
    for (int n = 0; n < MR; ++n) {
      int r = (wc * HALF + n * 16 + fr) * LDB + fq * 8;
      wh[n] = *(const bf16x8*)&Wh[r];
      wl[n] = *(const bf16x8*)&Wl[r];
    }
#pragma unroll
    for (int m = 0; m < MR; ++m)
#pragma unroll
      for (int n = 0; n < MR; ++n) {
        acc[m][n] = __builtin_amdgcn_mfma_f32_16x16x32_bf16(ah[m], wh[n], acc[m][n], 0, 0, 0);
        acc[m][n] = __builtin_amdgcn_mfma_f32_16x16x32_bf16(al[m], wh[n], acc[m][n], 0, 0, 0);
        acc[m][n] = __builtin_amdgcn_mfma_f32_16x16x32_bf16(ah[m], wl[n], acc[m][n], 0, 0, 0);
      }
  };

  // prologue: A step 0; W steps 0 and 1
  loadA(a0, a1, 0);
  loadW(wA0, wA1, 0);
  loadW(wB0, wB1, BKG);

  for (int step = 0; step < nsteps; step += 2) {
    // ---- even step: consume a*, wA* ----
    writeTiles(a0, a1, wA0, wA1);
    loadA(a0, a1, (step + 1) * BKG);
    if (step + 2 < nsteps) loadW(wA0, wA1, (step + 2) * BKG);
    __syncthreads();
    mfmaStep();
    __syncthreads();
    // ---- odd step: consume a*, wB* ----
    writeTiles(a0, a1, wB0, wB1);
    if (step + 2 < nsteps) loadA(a0, a1, (step + 2) * BKG);
    if (step + 3 < nsteps) loadW(wB0, wB1, (step + 3) * BKG);
    __syncthreads();
    mfmaStep();
    __syncthreads();
  }

  if (!geglu) {
#pragma unroll
    for (int m = 0; m < MR; ++m)
#pragma unroll
      for (int n = 0; n < MR; ++n) {
        int col = n0 + wc * HALF + n * 16 + fr;
        if (col >= Neff) continue;
        float bv = biasb ? biasb[col] : 0.f;
#pragma unroll
        for (int j = 0; j < 4; ++j) {
          int row = m0 + wr * HALF + m * 16 + fq * 4 + j;
          if (row < M) Cb[(size_t)row * ld + col] = acc[m][n][j] + bv;
        }
      }
  } else {
    // GEGLU: even col = sim, odd col = gate (interleaved weight rows).
#pragma unroll
    for (int m = 0; m < MR; ++m)
#pragma unroll
      for (int n = 0; n < MR; ++n) {
        int col = n0 + wc * HALF + n * 16 + fr;
        float bv = biasb[col];
#pragma unroll
        for (int j = 0; j < 4; ++j) {
          float z = acc[m][n][j] + bv;
          float zn = __shfl_xor(z, 1);   // partner: sim<->gate
          if (!(col & 1) && col < Neff) {
            float g = zn;
            float a = z * (0.5f * g * (1.f + erff(g * 0.70710678118654752f)));
            int row = m0 + wr * HALF + m * 16 + fq * 4 + j;
            if (row < M) Cb[(size_t)row * ld + (col >> 1)] = a;
          }
        }
      }
  }
}

// ====== FF-keys weight perm+pad: [6,2730,512] -> [6,2816,512] interleaved ==
__global__ void ffk_perm_kernel(const float* __restrict__ kw,
                                const float* __restrict__ kb,
                                float* __restrict__ wout, float* __restrict__ bout)
{
  size_t idx = (size_t)blockIdx.x * 256 + threadIdx.x;
  const size_t per = 2816ull * 512;
  if (idx < 6 * per) {
    int b = (int)(idx / per);
    size_t r2 = idx % per;
    int r = (int)(r2 >> 9), k = (int)(r2 & 511);
    float v = 0.f;
    if (r < 2730) {
      int c = (r >> 1) + (r & 1) * 1365;
      v = kw[((size_t)b * 2730 + c) * 512 + k];
    }
    wout[idx] = v;
  }
  if (idx < 6 * 2816) {
    int b = (int)(idx / 2816), r = (int)(idx % 2816);
    float v = 0.f;
    if (r < 2730) {
      int c = (r >> 1) + (r & 1) * 1365;
      v = kb[(size_t)b * 2730 + c];
    }
    bout[idx] = v;
  }
}

// ====== FF-vals weight pad: [6,512,1365] -> [6,512,1408] (K zero-pad) ======
__global__ void ffv_pad_kernel(const float* __restrict__ vw, float* __restrict__ wout)
{
  size_t idx = (size_t)blockIdx.x * 256 + threadIdx.x;
  const size_t total = 6ull * 512 * 1408;
  if (idx >= total) return;
  int k = (int)(idx % 1408);
  size_t nr = idx / 1408;   // b*512 + n
  wout[idx] = (k < 1365) ? vw[nr * 1365 + k] : 0.f;
}

// ================= rmsnorm over dim 512 (fp32 -> fp32) =====================
__global__ __launch_bounds__(256) void rmsnorm_kernel(
    const float* __restrict__ x, const float* __restrict__ w,
    float* __restrict__ out, int rows_per_w)
{
  int r = blockIdx.x;
  int t = threadIdx.x;
  const float* xr = x + (size_t)r * 512;
  float a = xr[t], b = xr[t + 256];
  float ss = a * a + b * b;
  for (int off = 32; off; off >>= 1) ss += __shfl_xor(ss, off);
  __shared__ float wsum[4];
  if ((t & 63) == 0) wsum[t >> 6] = ss;
  __syncthreads();
  float tot = wsum[0] + wsum[1] + wsum[2] + wsum[3];
  float rs = rsqrtf(tot * (1.f / 512.f) + EPSV);
  const float* wr = w + (size_t)(r / rows_per_w) * 512;
  out[(size_t)r * 512 + t] = a * rs * wr[t];
  out[(size_t)r * 512 + t + 256] = b * rs * wr[t + 256];
}

// ==== triple-output rmsnorm: one stats pass, three weights/outputs =========
__global__ __launch_bounds__(256) void rmsnorm3_kernel(
    const float* __restrict__ x, const float* __restrict__ w1,
    const float* __restrict__ w2, const float* __restrict__ w3,
    float* __restrict__ o1, float* __restrict__ o2, float* __restrict__ o3,
    int rows_per_w)
{
  int r = blockIdx.x;
  int t = threadIdx.x;
  const float* xr = x + (size_t)r * 512;
  float a = xr[t], b = xr[t + 256];
  float ss = a * a + b * b;
  for (int off = 32; off; off >>= 1) ss += __shfl_xor(ss, off);
  __shared__ float wsum[4];
  if ((t & 63) == 0) wsum[t >> 6] = ss;
  __syncthreads();
  float tot = wsum[0] + wsum[1] + wsum[2] + wsum[3];
  float rs = rsqrtf(tot * (1.f / 512.f) + EPSV);
  int wrow = r / rows_per_w;
  float ar = a * rs, br = b * rs;
  o1[(size_t)r * 512 + t]       = ar * w1[(size_t)wrow * 512 + t];
  o1[(size_t)r * 512 + t + 256] = br * w1[(size_t)wrow * 512 + t + 256];
  o2[(size_t)r * 512 + t]       = ar * w2[(size_t)wrow * 512 + t];
  o2[(size_t)r * 512 + t + 256] = br * w2[(size_t)wrow * 512 + t + 256];
  o3[(size_t)r * 512 + t]       = ar * w3[t];
  o3[(size_t)r * 512 + t + 256] = br * w3[t + 256];
}

// ================= broadcast tokens -> toks[L] =============================
__global__ void bcast_kernel(const float* __restrict__ tokens, float* __restrict__ toks)
{
  size_t idx = (size_t)blockIdx.x * 256 + threadIdx.x;
  const size_t total = (size_t)6 * 2 * 192 * 512;
  if (idx >= total) return;
  toks[idx] = tokens[idx % ((size_t)2 * 192 * 512)];
}

// ====== block self-attention, LDS K then V, 8 waves x 2 queries ===========
__global__ __launch_bounds__(512) void block_attn_kernel(
    const float* __restrict__ q, const float* __restrict__ kv, float* __restrict__ o)
{
  int h = blockIdx.y, lb = blockIdx.z;
  int t = threadIdx.x;
  int wave = t >> 6, lane = t & 63;
  int i0 = blockIdx.x * 16 + wave * 2;

  __shared__ float Ks[192][65];    // 49,920 B (K, then reused for V)
  __shared__ float qs[8][2][64];   // 4 KB
  __shared__ float ps[16][192];    // 12 KB

  const float* kb = kv + (size_t)lb * 192 * 1024 + h * 64;
#pragma unroll
  for (int c = 0; c < 24; ++c) {
    int idx = c * 512 + t;
    int row = idx >> 6, col = idx & 63;
    Ks[row][col] = kb[(size_t)row * 1024 + col];
  }
#pragma unroll
  for (int qq = 0; qq < 2; ++qq)
    qs[wave][qq][lane] = q[((size_t)(lb * 192 + i0 + qq)) * 512 + h * 64 + lane];
  __syncthreads();

  float s[2][3];
#pragma unroll
  for (int r = 0; r < 3; ++r) {
    int j = lane + r * 64;
    float a0 = 0.f, a1 = 0.f;
#pragma unroll 8
    for (int d = 0; d < 64; ++d) {
      float kvl = Ks[j][d];
      a0 += qs[wave][0][d] * kvl;
      a1 += qs[wave][1][d] * kvl;
    }
    s[0][r] = a0;
    s[1][r] = a1;
  }
#pragma unroll
  for (int qq = 0; qq < 2; ++qq) {
    float mx = fmaxf(fmaxf(s[qq][0], s[qq][1]), s[qq][2]);
    for (int off = 32; off; off >>= 1) mx = fmaxf(mx, __shfl_xor(mx, off));
    float sum = 0.f;
#pragma unroll
    for (int r = 0; r < 3; ++r) { s[qq][r] = expf(s[qq][r] - mx); sum += s[qq][r]; }
    for (int off = 32; off; off >>= 1) sum += __shfl_xor(sum, off);
    float inv = 1.f / sum;
#pragma unroll
    for (int r = 0; r < 3; ++r) ps[wave * 2 + qq][lane + r * 64] = s[qq][r] * inv;
  }

  // ---- phase 2: stage V over K (all waves done with Ks), PV from LDS ----
  __syncthreads();
  const float* vb = kb + 512;
#pragma unroll
  for (int c = 0; c < 24; ++c) {
    int idx = c * 512 + t;
    int row = idx >> 6, col = idx & 63;
    Ks[row][col] = vb[(size_t)row * 1024 + col];
  }
  __syncthreads();
  float acc0 = 0.f, acc1 = 0.f;
  for (int j = 0; j < 192; ++j) {
    float v = Ks[j][lane];
    acc0 += ps[wave * 2][j] * v;
    acc1 += ps[wave * 2 + 1][j] * v;
  }
  o[((size_t)(lb * 192 + i0)) * 512 + h * 64 + lane] = acc0;
  o[((size_t)(lb * 192 + i0 + 1)) * 512 + h * 64 + lane] = acc1;
}

// ================= pooled attention, K/V amortized over 6 queries ==========
__global__ __launch_bounds__(64) void pooled_attn_kernel(
    const float* __restrict__ q, const float* __restrict__ Kc,
    const float* __restrict__ Vc, float* __restrict__ o, int M, int mode)
{
  int n = blockIdx.x, h = blockIdx.y, z = blockIdx.z;
  int lane = threadIdx.x;
  int nq = mode ? 1 : 6;

  __shared__ float Ks[80][65];    // 20,800 B
  __shared__ float qs[6][64];
  __shared__ float p[6][128];

  for (int m = 0; m < M; ++m)
    Ks[m][lane] = Kc[(((size_t)m * 2 + z) * 192 + n) * 512 + h * 64 + lane];
  for (int jj = 0; jj < nq; ++jj) {
    const float* qrow = mode ? (q + h * 64)
                             : (q + ((size_t)((z * 6 + jj) * 192 + n)) * 512 + h * 64);
    qs[jj][lane] = qrow[lane];
  }
  __syncthreads();

  float d0[6] = {}, d1[6] = {};
  int m1 = lane + 64;
#pragma unroll 4
  for (int d = 0; d < 64; ++d) {
    float k0 = Ks[lane][d];
    float k1 = Ks[m1 & 79][d];
#pragma unroll
    for (int jj = 0; jj < 6; ++jj) {
      float qv = qs[jj][d];
      d0[jj] += qv * k0;
      d1[jj] += qv * k1;
    }
  }
  float acc[6] = {};
#pragma unroll
  for (int jj = 0; jj < 6; ++jj) {
    if (jj >= nq) break;
    float s0 = (lane < M) ? d0[jj] : -1e30f;
    float s1 = (m1 < M) ? d1[jj] : -1e30f;
    float mx = fmaxf(s0, s1);
    for (int off = 32; off; off >>= 1) mx = fmaxf(mx, __shfl_xor(mx, off));
    float e0 = (lane < M) ? expf(s0 - mx) : 0.f;
    float e1 = (m1 < M) ? expf(s1 - mx) : 0.f;
    float sum = e0 + e1;
    for (int off = 32; off; off >>= 1) sum += __shfl_xor(sum, off);
    float inv = 1.f / sum;
    p[jj][lane] = e0 * inv;
    p[jj][m1] = e1 * inv;
  }
  __syncthreads();

  for (int m = 0; m < M; ++m) {
    float v = Vc[(((size_t)m * 2 + z) * 192 + n) * 512 + h * 64 + lane];
#pragma unroll
    for (int jj = 0; jj < 6; ++jj) acc[jj] += p[jj][m] * v;
  }
#pragma unroll
  for (int jj = 0; jj < 6; ++jj) {
    if (jj >= nq) break;
    int orow = mode ? (z * 192 + n) : ((z * 6 + jj) * 192 + n);
    o[(size_t)orow * 512 + h * 64 + lane] = acc[jj];
  }
}

// ========= kv-cache fill, K-only (per-head key rmsnorm) ====================
__global__ __launch_bounds__(128) void cache_fill_kernel(
    const float* __restrict__ kvk, const float* __restrict__ knw,
    float* __restrict__ Kc, int base_e)
{
  int n = blockIdx.x;
  int t = blockIdx.y;
  int g = t >> 1, b = t & 1;
  int e = base_e + g;
  int lane = threadIdx.x;  // 128 lanes x 4 cols; 16 lanes per head
  const float* src = kvk + ((size_t)t * 192 + n) * 512;
  float k4[4];
  float ss = 0.f;
#pragma unroll
  for (int u = 0; u < 4; ++u) { k4[u] = src[lane * 4 + u]; ss += k4[u] * k4[u]; }
  for (int off = 8; off; off >>= 1) ss += __shfl_xor(ss, off, 16);
  float rs = rsqrtf(ss * (1.f / 64.f) + EPSV);
  float* kd = Kc + (((size_t)e * 2 + b) * 192 + n) * 512;
#pragma unroll
  for (int u = 0; u < 4; ++u) {
    int c = lane * 4 + u;
    kd[c] = k4[u] * rs * knw[c & 63];
  }
}

// ===========================================================================
extern "C" void kernel_launch(void* const* d_in, const int* in_sizes, int n_in,
                              void* d_out, int out_size, void* d_ws, size_t ws_size,
                              hipStream_t stream)
{
  const float* tokens   = (const float*)d_in[0];
  const float* attn_nw  = (const float*)d_in[1];
  const float* attn_qw  = (const float*)d_in[2];
  const float* attn_kvw = (const float*)d_in[3];
  const float* attn_ow  = (const float*)d_in[4];
  const float* ff_nw    = (const float*)d_in[5];
  const float* ff_kw    = (const float*)d_in[6];
  const float* ff_kb    = (const float*)d_in[7];
  const float* ff_vw    = (const float*)d_in[8];
  const float* ff_vb    = (const float*)d_in[9];
  const float* res_nw   = (const float*)d_in[10];
  const float* res_knw  = (const float*)d_in[11];
  const float* res_qw   = (const float*)d_in[12];
  const float* res_kvw  = (const float*)d_in[13];
  const float* res_ow   = (const float*)d_in[14];
  const float* q_ro     = (const float*)d_in[15];
  const float* ro_nw    = (const float*)d_in[16];
  const float* ro_w     = (const float*)d_in[17];
  float* out = (float*)d_out;

  // ---- workspace carve-up (55,461,376 floats = 221.9 MB) ----
  float* ws = (float*)d_ws;
  const size_t NEED = 55461376ull * 4ull;
  if (ws_size < NEED) return;
  float* ffk_w   = ws;  ws += 6ull * 2816 * 512;   // 8,650,752 (perm+pad fp32)
  float* ffk_b   = ws;  ws += 6ull * 2816;         // 16,896
  float* ffv_w   = ws;  ws += 6ull * 512 * 1408;   // 4,325,376 (K-pad fp32)
  float* toks    = ws;  ws += 1179648;             // [6,2,192,512]
  float* hbuf    = ws;  ws += 2359296;             // [<=4608,512]
  float* hbuf3   = ws;  ws += 1179648;             // res-normed toks (persistent)
  float* msgbuf  = ws;  ws += 2359296;             // [2,6,2,192,512]
  float* scratch = ws;  ws += 4718592;             // union region
  float* rqn     = ws;  ws += 512;
  float* rq      = ws;  ws += 512;
  float* Kc      = ws;  ws += 15335424;            // [78,2,192,512], entry stride 196608
  float* Vc      = ws;  ws += 15335424;            // [78,2,192,512], entry stride 196608
  // scratch union (all uses strictly serialized on `stream`):
  float* qbuf   = scratch;                 // [2304,512]
  float* kvbuf  = scratch + 1179648;       // [12,192,1024]
  float* obuf   = scratch + 3538944;       // [2304,512]
  float* kvk    = scratch;                 // [<=24,192,512] = 2,359,296
  float* act    = scratch;                 // [2304,1408] = 3,244,032
  float* hbuf2  = hbuf + 1179648;          // ff-normed rows (dead before 4608-row rmsnorm)
  // readout aliases (msgbuf dead by then):
  float* robuf  = msgbuf;                  // [384,512]
  float* robuf2 = msgbuf + 196608;         // [384,512]
  float* ronorm = msgbuf + 393216;         // [384,512]

  auto gemm = [&](const float* A, const float* W, const float* bias, float* C,
                  int M, int N, int K, int ldc,
                  long long aStr, long long wStr, long long bStr, long long cStr,
                  int nb, int mode) {
    int gx = (N + 127) / 128, gy = (M + 127) / 128;
    if (mode == 0 && gx * gy * nb <= 300) {
      dim3 g((M + 63) / 64, (N + 63) / 64, nb);   // x = m-tiles, y = n-tiles
      hipLaunchKernelGGL((gemm_split_t<64, 2>), g, dim3(256), 0, stream,
                         A, A, W, W, bias, C, C, M, N, N, K, ldc, ldc,
                         aStr, 0ll, wStr, 0ll, bStr, cStr, 0ll, mode);
    } else {
      dim3 g(gy, gx, nb);                          // x = m-tiles, y = n-tiles
      hipLaunchKernelGGL((gemm_split_t<128, 4>), g, dim3(256), 0, stream,
                         A, A, W, W, bias, C, C, M, N, N, K, ldc, ldc,
                         aStr, 0ll, wStr, 0ll, bStr, cStr, 0ll, mode);
    }
  };
  // merged dual-output GEMM (mode 2), 64^2 tiles (same A both halves)
  auto gemm2 = [&](const float* A, const float* W, const float* W2,
                   float* C, float* C2, int M, int N, int Nsplit, int K,
                   int ldc, int ldc2, long long aStr, long long wStr,
                   long long wStr2, long long cStr, long long cStr2, int nb) {
    dim3 g((M + 63) / 64, (N + 63) / 64, nb);
    hipLaunchKernelGGL((gemm_split_t<64, 2>), g, dim3(256), 0, stream,
                       A, A, W, W2, nullptr, C, C2, M, N, Nsplit, K, ldc, ldc2,
                       aStr, 0ll, wStr, wStr2, 0ll, cStr, cStr2, 2);
  };
  // merged dual-kernel GEMM (mode 3): part1 plain A*W->C, part2 GEGLU
  auto gemm3 = [&](const float* A, const float* A2, const float* W,
                   const float* W2, const float* bias, float* C, float* C2,
                   int M, int N, int Nsplit, int K, int ldc, int ldc2,
                   long long aStr, long long aStr2, long long wStr,
                   long long wStr2, long long bStr, long long cStr,
                   long long cStr2, int nb) {
    dim3 g((M + 63) / 64, (N + 63) / 64, nb);
    hipLaunchKernelGGL((gemm_split_t<64, 2>), g, dim3(256), 0, stream,
                       A, A2, W, W2, bias, C, C2, M, N, Nsplit, K, ldc, ldc2,
                       aStr, aStr2, wStr, wStr2, bStr, cStr, cStr2, 3);
  };
  // kv-cache GEMM: K half -> kvk (compact), V half -> Vc directly (mode 2).
  // Vc entry stride is 196608 floats ([2][192][512] per entry); batch z of
  // the GEMM covers entry base+z: offset = z*196608 + row*512 + (col-512).
  auto gemmKV = [&](const float* A, float* Vdst, int nb) {
    dim3 g(6, 16, nb);   // 384/64 m-tiles, 1024/64 n-tiles
    hipLaunchKernelGGL((gemm_split_t<64, 2>), g, dim3(256), 0, stream,
                       A, A, res_kvw, res_kvw + 512 * 512, nullptr, kvk, Vdst,
                       384, 1024, 512, 512, 512, 512,
                       196608ll, 0ll, 0ll, 0ll, 0ll, 196608ll, 196608ll, 2);
  };

  // ---- FF weight prep (perm+pad) ----
  hipLaunchKernelGGL(ffk_perm_kernel, dim3((unsigned)((6ull * 2816 * 512 + 255) / 256)),
                     dim3(256), 0, stream, ff_kw, ff_kb, ffk_w, ffk_b);
  hipLaunchKernelGGL(ffv_pad_kernel, dim3((unsigned)((6ull * 512 * 1408 + 255) / 256)),
                     dim3(256), 0, stream, ff_vw, ffv_w);

  // ---- init: toks = broadcast(tokens); cache msg0 kv entries 0..5 ----
  {
    const int total = 6 * 2 * 192 * 512;
    hipLaunchKernelGGL(bcast_kernel, dim3((total + 255) / 256), dim3(256), 0, stream,
                       tokens, toks);
  }
  hipLaunchKernelGGL(rmsnorm_kernel, dim3(2304), dim3(256), 0, stream,
                     toks, res_nw, hbuf, 2304);
  gemmKV(hbuf, Vc, 6);   // entries 0..5: V direct, K -> kvk
  hipLaunchKernelGGL(cache_fill_kernel, dim3(192, 12), dim3(128), 0, stream,
                     kvk, res_knw, Kc, 0);

  for (int it = 0; it < 6; ++it) {
    // ---- norms for all three consumers of toks (one stats pass) ----
    hipLaunchKernelGGL(rmsnorm3_kernel, dim3(2304), dim3(256), 0, stream,
                       toks, attn_nw, ff_nw, res_nw, hbuf, hbuf2, hbuf3, 384);
    // ---- block self-attention -> msgbuf[0] (q+kv in ONE dispatch) ----
    gemm2(hbuf, attn_qw, attn_kvw, qbuf, kvbuf, 384, 1536, 512, 512, 512, 1024,
          196608, 262144, 524288, 196608, 393216, 6);
    hipLaunchKernelGGL(block_attn_kernel, dim3(12, 8, 12), dim3(512), 0, stream,
                       qbuf, kvbuf, obuf);
    // ---- attn-out + FF-keys GEGLU merged (both K=512) ----
    gemm3(obuf, hbuf2, attn_ow, ffk_w, ffk_b, msgbuf, act,
          384, 512 + 2730, 512, 512, 512, 1408,
          196608, 196608, 262144, 1441792, 2816, 196608, 540672, 6);
    // ---- FF-vals -> msgbuf[1] ----
    gemm(act, ffv_w, ff_vb, msgbuf + 1179648, 384, 512, 1408, 512,
         540672, 720896, 512, 196608, 6, 0);
    // ---- cache kv for the two new messages (V direct to Vc) ----
    hipLaunchKernelGGL(rmsnorm_kernel, dim3(4608), dim3(256), 0, stream,
                       msgbuf, res_nw, hbuf, 4608);
    gemmKV(hbuf, Vc + (size_t)(2 * it + 1) * 6 * 196608, 12);  // clobbers act (dead)
    hipLaunchKernelGGL(cache_fill_kernel, dim3(192, 24), dim3(128), 0, stream,
                       kvk, res_knw, Kc, (2 * it + 1) * 6);
    if (it == 5) break;
    // ---- pooled cross-attention over all cached entries -> new toks ----
    gemm(hbuf3, res_qw, nullptr, qbuf, 2304, 512, 512, 512,
         0, 0, 0, 0, 1, 0);                          // clobbers kvk (dead)
    hipLaunchKernelGGL(pooled_attn_kernel, dim3(192, 8, 2), dim3(64), 0, stream,
                       qbuf, Kc, Vc, obuf, (3 + 2 * it) * 6, 0);
    gemm(obuf, res_ow, nullptr, toks, 2304, 512, 512, 512,
         0, 0, 0, 0, 1, 0);
  }

  // ---- readout ----
  hipLaunchKernelGGL(rmsnorm_kernel, dim3(1), dim3(256), 0, stream,
                     q_ro, res_nw, rqn, 1);
  gemm(rqn, res_qw, nullptr, rq, 1, 512, 512, 512, 0, 0, 0, 0, 1, 0);
  hipLaunchKernelGGL(pooled_attn_kernel, dim3(192, 8, 2), dim3(64), 0, stream,
                     rq, Kc, Vc, robuf, 78, 1);
  gemm(robuf, res_ow, nullptr, robuf2, 384, 512, 512, 512, 0, 0, 0, 0, 1, 0);
  hipLaunchKernelGGL(rmsnorm_kernel, dim3(384), dim3(256), 0, stream,
                     robuf2, ro_nw, ronorm, 384);
  gemm(ronorm, ro_w, nullptr, out, 384, 32000, 512, 32000, 0, 0, 0, 0, 1, 0);
}